// Round 20
// baseline (194.256 us; speedup 1.0000x reference)
//
#include <hip/hip_runtime.h>
#include <stdint.h>
#include <math.h>

#define NB 4
#define NU 1024
#define NS 256
#define NF 16
#define ND 256
#define NEGV -1000000000.0f
#define VBIT (1u << 14)
#define AGENT __HIP_MEMORY_SCOPE_AGENT
#define SPINCAP (1 << 20)
#define NGRP 64            // blocks per batch
#define SPB 4              // servers per block
#define NT 1024            // threads per step-block (16 waves)

// propA[par+bs]: bits0-9 argu | 10-13 fid | 14 valid | 15-20 epoch ; maxv bits << 32
// propB[par+bs]: low32 = -log(sum) bits ; high32 = epoch

// ---- shared 64x64 f32 GEMM body (double-buffered LDS; proven bit-identical) ----
__device__ __forceinline__ void gemm64_body(
    const float* __restrict__ A, const float* __restrict__ Bm, float* __restrict__ C,
    int K, int lda, int ldb, int ldc, const float* __restrict__ biasA, float alpha,
    int m0, int n0, int t,
    float (&As)[2][16][68], float (&Bs)[2][16][68]) {
  int tx = t & 15, ty = t >> 4;
  float acc[4][4];
#pragma unroll
  for (int i = 0; i < 4; i++)
#pragma unroll
    for (int j = 0; j < 4; j++) acc[i][j] = 0.f;
  int lr = t >> 2;
  int kq = (t & 3) * 4;
  {
    float4 av = *(const float4*)(A + (size_t)(m0 + lr) * lda + kq);
    if (biasA) {
      const float* bp = biasA + kq;
      av.x += bp[0]; av.y += bp[1]; av.z += bp[2]; av.w += bp[3];
    }
    As[0][kq + 0][lr] = av.x; As[0][kq + 1][lr] = av.y;
    As[0][kq + 2][lr] = av.z; As[0][kq + 3][lr] = av.w;
    float4 bv = *(const float4*)(Bm + (size_t)(n0 + lr) * ldb + kq);
    Bs[0][kq + 0][lr] = bv.x; Bs[0][kq + 1][lr] = bv.y;
    Bs[0][kq + 2][lr] = bv.z; Bs[0][kq + 3][lr] = bv.w;
  }
  __syncthreads();
  int nt = K >> 4;
  for (int ti = 0; ti < nt; ++ti) {
    int buf = ti & 1;
    float4 av2, bv2;
    bool more = (ti + 1 < nt);
    if (more) {
      int k0 = (ti + 1) << 4;
      av2 = *(const float4*)(A + (size_t)(m0 + lr) * lda + k0 + kq);
      if (biasA) {
        const float* bp = biasA + k0 + kq;
        av2.x += bp[0]; av2.y += bp[1]; av2.z += bp[2]; av2.w += bp[3];
      }
      bv2 = *(const float4*)(Bm + (size_t)(n0 + lr) * ldb + k0 + kq);
    }
#pragma unroll
    for (int k = 0; k < 16; ++k) {
      float4 a = *(const float4*)&As[buf][k][ty * 4];
      float4 bb = *(const float4*)&Bs[buf][k][tx * 4];
      float am[4] = {a.x, a.y, a.z, a.w};
      float bn[4] = {bb.x, bb.y, bb.z, bb.w};
#pragma unroll
      for (int i = 0; i < 4; ++i)
#pragma unroll
        for (int j = 0; j < 4; ++j) acc[i][j] += am[i] * bn[j];
    }
    if (more) {
      __syncthreads();
      int nb = buf ^ 1;
      As[nb][kq + 0][lr] = av2.x; As[nb][kq + 1][lr] = av2.y;
      As[nb][kq + 2][lr] = av2.z; As[nb][kq + 3][lr] = av2.w;
      Bs[nb][kq + 0][lr] = bv2.x; Bs[nb][kq + 1][lr] = bv2.y;
      Bs[nb][kq + 2][lr] = bv2.z; Bs[nb][kq + 3][lr] = bv2.w;
      __syncthreads();
    }
  }
#pragma unroll
  for (int i = 0; i < 4; ++i) {
    float4 o = make_float4(acc[i][0] * alpha, acc[i][1] * alpha,
                           acc[i][2] * alpha, acc[i][3] * alpha);
    *(float4*)(C + (size_t)(m0 + ty * 4 + i) * ldc + n0 + tx * 4) = o;
  }
}

// ---- pre1: transpose(+local dtype detect) | weights | q-gemm | kb-gemm | prop-zero ----
__global__ __launch_bounds__(256) void k_pre1(
    const uint8_t* __restrict__ conn, const float* __restrict__ W_state,
    const float* __restrict__ W_k, const float* __restrict__ user_enc,
    const float* __restrict__ server_enc, const float* __restrict__ b_state,
    const float* __restrict__ W_q,
    uint32_t* __restrict__ connT, float* __restrict__ WS_K,
    float* __restrict__ q, float* __restrict__ kb, float4* __restrict__ propZ) {
  __shared__ float As[2][16][68];
  __shared__ float Bs[2][16][68];
  int blk = blockIdx.x;
  int t = threadIdx.x;
  if (blk < 128) {
    __shared__ unsigned dd[2];
    unsigned c0 = 0, c123 = 0;
    for (int i = t; i < 4096; i += 256) {
      uchar4 v = ((const uchar4*)conn)[i];
      c0 |= v.x; c123 |= (unsigned)(v.y | v.z | v.w);
    }
    if (t == 0) { dd[0] = 0; dd[1] = 0; }
    __syncthreads();
    unsigned long long m0 = __ballot(c0 != 0), m1 = __ballot(c123 != 0);
    if ((t & 63) == 0) {
      if (m0) atomicOr(&dd[0], 1u);
      if (m1) atomicOr(&dd[1], 1u);
    }
    __syncthreads();
    int f = (dd[1] == 0) ? 0 : ((dd[0] == 0) ? 1 : 2);
    int b = blk >> 5, ug = blk & 31;
    int u0 = ug * 32;
    uint8_t* sm = (uint8_t*)&As[0][0][0];   // 8320B < 8704B
#pragma unroll 4
    for (int r = 0; r < 32; ++r) {
      int e = (b * NU + u0 + r) * NS + t;
      bool nz;
      if (f == 0)      nz = ((const int*)conn)[e] != 0;
      else if (f == 1) nz = ((const float*)conn)[e] != 0.0f;
      else             nz = conn[e] != 0;
      sm[r * 260 + t] = nz ? 1 : 0;
    }
    __syncthreads();
    uint32_t word = 0;
#pragma unroll
    for (int j = 0; j < 32; ++j) word |= (uint32_t)sm[j * 260 + t] << j;
    connT[(b * NS + t) * 32 + ug] = word;
  } else if (blk == 128) {
    int d = t;
    const float4* wk4 = (const float4*)(W_k + d * ND);
    const float4* ws4 = (const float4*)W_state;
    float a0 = 0, a1 = 0, a2 = 0, a3 = 0;
    for (int e4 = 0; e4 < ND / 4; ++e4) {
      float4 k4 = wk4[e4];
      float4 w0 = ws4[e4 * 4 + 0];
      a0 += k4.x * w0.x; a1 += k4.x * w0.y; a2 += k4.x * w0.z; a3 += k4.x * w0.w;
      float4 w1 = ws4[e4 * 4 + 1];
      a0 += k4.y * w1.x; a1 += k4.y * w1.y; a2 += k4.y * w1.z; a3 += k4.y * w1.w;
      float4 w2 = ws4[e4 * 4 + 2];
      a0 += k4.z * w2.x; a1 += k4.z * w2.y; a2 += k4.z * w2.z; a3 += k4.z * w2.w;
      float4 w3 = ws4[e4 * 4 + 3];
      a0 += k4.w * w3.x; a1 += k4.w * w3.y; a2 += k4.w * w3.z; a3 += k4.w * w3.w;
    }
    ((float4*)WS_K)[d] = make_float4(a0, a1, a2, a3);
  } else if (blk < 385) {
    int idx = blk - 129;           // q-gemm: M=4096, N=256 -> 64x4 tiles = 256 blocks
    gemm64_body(user_enc, W_q, q, ND, ND, ND, ND, nullptr, 1.f,
                (idx >> 2) * 64, (idx & 3) * 64, t, As, Bs);
  } else if (blk < 449) {
    int idx = blk - 385;           // kb-gemm: M=1024, N=256 -> 16x4 tiles = 64 blocks
    gemm64_body(server_enc, W_k, kb, ND, ND, ND, ND, b_state, 1.f,
                (idx >> 2) * 64, (idx & 3) * 64, t, As, Bs);
  } else {
    float4 z = make_float4(0.f, 0.f, 0.f, 0.f);
    for (int i = t; i < 2048; i += 256) propZ[i] = z;   // propA+propB 32KB contiguous
  }
}

// ---- pre2: qc | L0T-gemm ----
__global__ __launch_bounds__(256) void k_pre2(const float* __restrict__ q,
                                              const float* __restrict__ WS_K,
                                              float* __restrict__ qc,
                                              const float* __restrict__ kb,
                                              float* __restrict__ L0T) {
  __shared__ float As[2][16][68];
  __shared__ float Bs[2][16][68];
  int blk = blockIdx.x;
  int t = threadIdx.x;
  if (blk < 1024) {
    int row = blk * 4 + (t >> 6);
    int ln = t & 63;
    const float* qr = q + (size_t)row * ND;
    float a0 = 0, a1 = 0, a2 = 0, a3 = 0;
    for (int d = ln; d < ND; d += 64) {
      float qv = qr[d];
      float4 w = ((const float4*)WS_K)[d];
      a0 += qv * w.x; a1 += qv * w.y; a2 += qv * w.z; a3 += qv * w.w;
    }
    for (int o = 32; o; o >>= 1) {
      a0 += __shfl_xor(a0, o); a1 += __shfl_xor(a1, o);
      a2 += __shfl_xor(a2, o); a3 += __shfl_xor(a3, o);
    }
    if (ln == 0)
      ((float4*)qc)[row] = make_float4(a0 * 0.0625f, a1 * 0.0625f, a2 * 0.0625f, a3 * 0.0625f);
  } else {
    int idx = blk - 1024;          // L0T: per batch z, M=NS (4 tiles), N=NU (16 tiles)
    int z = idx >> 6;
    int rest = idx & 63;
    int m0 = (rest >> 4) * 64;
    int n0 = (rest & 15) * 64;
    gemm64_body(kb + (size_t)z * NS * ND, q + (size_t)z * NU * ND,
                L0T + (size_t)z * NS * NU, ND, ND, ND, NU, nullptr, 0.0625f,
                m0, n0, t, As, Bs);
  }
}

// ---- the 32-step allocator: 4 barriers/step (fused rescaled-lse reduction),
//      single 64-bit key atomic, deferred propB ----
__global__ __launch_bounds__(NT) void k_steps4(
    const float* __restrict__ L0T, const float* __restrict__ qc,
    const float* __restrict__ users, const float* __restrict__ servers,
    const uint32_t* __restrict__ connT, const float* __restrict__ fd_onehot,
    const float* __restrict__ W_us, const float* __restrict__ fd_alpha,
    const float* __restrict__ fd_beta, const float* __restrict__ score_bias,
    unsigned long long* __restrict__ propA, unsigned long long* __restrict__ propB,
    float* __restrict__ out) {
  __shared__ float redM[SPB][NT];
  __shared__ int redA[SPB][NT];
  __shared__ unsigned long long key64[4][NU];   // 32KB: enc<<32 | (255-srv)
  __shared__ float lsum4[4][NU];
  __shared__ unsigned fdSh4[4][NU];
  __shared__ float4 capS4[SPB];
  __shared__ float4 crS4[SPB];
  __shared__ float4 minv4[SPB];
  __shared__ int fidS[SPB];
  __shared__ float pM[SPB][4];
  __shared__ int pA[SPB][4];
  __shared__ float pS[SPB][4];
  __shared__ float wredL[16];
  __shared__ int anyL[4];

  const int blk = blockIdx.x;
  // XCD-clustered bijection: batch b on XCD residues {2b, 2b+1}
  const int b = (blk & 7) >> 1;
  const int g = ((blk >> 3) << 1) | (blk & 1);
  const int tid = threadIdx.x;
  const int wv = tid >> 6, ln64 = tid & 63;
  const int bs0 = b * NS + g * SPB;
  const int bank = tid & 3;
  const int sW = wv >> 2, part = wv & 3;   // wave->server/quarter reduction mapping

  const float a_ = fd_alpha[0], be_ = fd_beta[0];
  const float t0 = tanhf(be_), t1 = tanhf(a_ + be_);
  const float sb = score_bias[0];
  const float w0 = W_us[0], w1 = W_us[1], w2 = W_us[2];

  if (tid < SPB) {
    int srow = bs0 + tid;
    int f = 0;
    for (int ff = 0; ff < NF; ++ff)
      if (fd_onehot[srow * NF + ff] > 0.5f) { f = ff; break; }
    fidS[tid] = f;
    float4 ic = make_float4(servers[srow * 8 + 3], servers[srow * 8 + 4],
                            servers[srow * 8 + 5], servers[srow * 8 + 6]);
    capS4[tid] = ic;
    float4 mv = make_float4(fmaxf(ic.x, 1e-6f), fmaxf(ic.y, 1e-6f),
                            fmaxf(ic.z, 1e-6f), fmaxf(ic.w, 1e-6f));
    minv4[tid] = mv;
    crS4[tid] = make_float4(ic.x / mv.x, ic.y / mv.y, ic.z / mv.z, ic.w / mv.w);
  }

  // per-thread user state: user u == tid of batch b
  const int gu = b * NU + tid;
  float4 q4 = *(const float4*)(qc + gu * 4);
  float2 nA = *(const float2*)(users + gu * 8 + 2);
  float2 nB2 = *(const float2*)(users + gu * 8 + 4);
  const float nax = nA.x, nay = nA.y, nbx = nB2.x, nby = nB2.y;
  float L0r[SPB];
  uint32_t upk = 0;                 // bits 0-15 fdmask, bits 16-17 rc
  float usv = w1;
  float logpv = 0.f;
  uint32_t cb = 0, ab = 0;          // bit s
  // deferred propB consumption state (tid<256 only meaningful)
  int prevPu = 0, prevSlot = 0;
  unsigned prevE = 0;
  bool prevValid = false;
#pragma unroll
  for (int s = 0; s < SPB; ++s) {
    L0r[s] = L0T[(size_t)(bs0 + s) * NU + tid];
    uint32_t word = connT[(bs0 + s) * 32 + (tid >> 5)];
    cb |= ((word >> (tid & 31)) & 1u) << s;
  }
  for (int i = tid; i < 4 * NU; i += NT) {
    (&key64[0][0])[i] = 0ull;
    (&lsum4[0][0])[i] = 0.f;
    (&fdSh4[0][0])[i] = 0u;
  }
  __syncthreads();

  for (int step = 0; step < 32; ++step) {
    unsigned e = (unsigned)(step + 1);
    // ---- phase A: per-thread logits for own user x 4 servers ----
#pragma unroll
    for (int s = 0; s < SPB; ++s) {
      float4 c = capS4[s];
      float4 cr = crS4[s];
      int fid = fidS[s];
      bool el = ((cb >> s) & 1u) && !((ab >> s) & 1u) &&
                ((upk & 0x30000u) != 0x30000u) &&
                c.x >= nax && c.y >= nay && c.z >= nbx && c.w >= nby;
      float tt = ((upk >> fid) & 1u) ? t0 : t1;
      float lg = L0r[s] + q4.x * cr.x + q4.y * cr.y + q4.z * cr.z + q4.w * cr.w +
                 sb + tt + usv;
      float cv = el ? lg : NEGV;
      redM[s][tid] = cv;
      redA[s][tid] = (cv > NEGV) ? tid : 0x7fffffff;
    }
    __syncthreads();                               // B1
    // fused wave reduce: quarter max+arg AND quarter rescaled exp-sum, one pass
    {
      int base = part * 256 + ln64;
      float v0 = redM[sW][base];       int a0 = redA[sW][base];
      float v1 = redM[sW][base + 64];  int a1 = redA[sW][base + 64];
      float v2 = redM[sW][base + 128]; int a2 = redA[sW][base + 128];
      float v3 = redM[sW][base + 192]; int a3 = redA[sW][base + 192];
      float m = v0; int a = a0;
      if (v1 > m || (v1 == m && a1 < a)) { m = v1; a = a1; }
      if (v2 > m || (v2 == m && a2 < a)) { m = v2; a = a2; }
      if (v3 > m || (v3 == m && a3 < a)) { m = v3; a = a3; }
      for (int o = 32; o; o >>= 1) {
        float ov = __shfl_xor(m, o); int oa = __shfl_xor(a, o);
        if (ov > m || (ov == m && oa < a)) { m = ov; a = oa; }
      }
      // m = quarter max (uniform across lanes); rescaled exp-sum vs m
      float ps = expf(v0 - m) + expf(v1 - m) + expf(v2 - m) + expf(v3 - m);
      for (int o = 32; o; o >>= 1) ps += __shfl_xor(ps, o);
      if (ln64 == 0) { pM[sW][part] = m; pA[sW][part] = a; pS[sW][part] = ps; }
    }
    __syncthreads();                               // B2
    if (tid < SPB) {
      float m = pM[tid][0]; int a = pA[tid][0];
#pragma unroll
      for (int j = 1; j < 4; ++j) {
        float v = pM[tid][j]; int aa = pA[tid][j];
        if (v > m || (v == m && aa < a)) { m = v; a = aa; }
      }
      // combine rescaled partials: ps = sum_q ps_q * exp(m_q - m)
      float ps = pS[tid][0] * expf(pM[tid][0] - m) + pS[tid][1] * expf(pM[tid][1] - m) +
                 pS[tid][2] * expf(pM[tid][2] - m) + pS[tid][3] * expf(pM[tid][3] - m);
      int au = (a == 0x7fffffff) ? 0 : a;
      unsigned validb = (m > -1e8f) ? VBIT : 0u;
      unsigned pinfo = (unsigned)au | ((unsigned)fidS[tid] << 10) | validb | (e << 15);
      unsigned long long Aw = (unsigned long long)pinfo |
                              ((unsigned long long)__float_as_uint(m) << 32);
      unsigned long long Bw = (unsigned long long)__float_as_uint(-logf(ps)) |
                              ((unsigned long long)e << 32);
      int par = (step & 1) * (NB * NS);
      __hip_atomic_store(&propA[par + bs0 + tid], Aw, __ATOMIC_RELAXED, AGENT);
      __hip_atomic_store(&propB[par + bs0 + tid], Bw, __ATOMIC_RELAXED, AGENT);
    }

    // ---- phase B: single propA poll; one 64-bit key atomic; deferred propB ----
    {
      int par = (step & 1) * (NB * NS) + b * NS;
      unsigned pi = 0;
      if (tid < 256) {
        unsigned long long Aw = __hip_atomic_load(&propA[par + tid], __ATOMIC_RELAXED, AGENT);
        if ((((unsigned)Aw >> 15) & 63u) != e) {
          int iters = 0;
          do {
            __builtin_amdgcn_s_sleep(1);
            Aw = __hip_atomic_load(&propA[par + tid], __ATOMIC_RELAXED, AGENT);
            if (++iters > SPINCAP) break;
          } while ((((unsigned)Aw >> 15) & 63u) != e);
        }
        pi = (unsigned)Aw;
        int pu = pi & 1023;
        // deferred: add prev step's lsum contribution (propB long since visible)
        if (prevValid) {
          unsigned long long Bw = __hip_atomic_load(&propB[prevSlot], __ATOMIC_RELAXED, AGENT);
          if ((unsigned)(Bw >> 32) != prevE) {
            int iters = 0;
            do {
              __builtin_amdgcn_s_sleep(1);
              Bw = __hip_atomic_load(&propB[prevSlot], __ATOMIC_RELAXED, AGENT);
              if (++iters > SPINCAP) break;
            } while ((unsigned)(Bw >> 32) != prevE);
          }
          atomicAdd(&lsum4[bank][prevPu], __uint_as_float((unsigned)Bw));
        }
        prevValid = (pi & VBIT) != 0;
        prevPu = pu;
        prevSlot = par + tid;
        prevE = e;
        if (pi & VBIT) {
          unsigned vb = (unsigned)(Aw >> 32);
          unsigned enc = (vb & 0x80000000u) ? ~vb : (vb | 0x80000000u);
          unsigned long long key = ((unsigned long long)enc << 32) |
                                   (unsigned)(255 - tid);
          atomicMax(&key64[bank][pu], key);
          atomicOr(&fdSh4[bank][pu], 1u << ((pi >> 10) & 15));
        }
      }
      unsigned long long mm = __ballot((pi & VBIT) != 0);
      if (wv < 4 && ln64 == 0) anyL[wv] = (mm != 0ull) ? 1 : 0;
      __syncthreads();                              // B3: atomics + prevAdd done
      if (!(anyL[0] | anyL[1] | anyL[2] | anyL[3])) break;  // batch frozen forever
      {
        int u = tid;
        unsigned long long k0 = key64[0][u], k1 = key64[1][u];
        unsigned long long k2 = key64[2][u], k3 = key64[3][u];
        unsigned long long gmax = max(max(k0, k1), max(k2, k3));
        if (gmax) {
          int win = 255 - (int)(gmax & 0xFFull);
          float ls = lsum4[0][u] + lsum4[1][u] + lsum4[2][u] + lsum4[3][u];
          unsigned fda = fdSh4[0][u] | fdSh4[1][u] | fdSh4[2][u] | fdSh4[3][u];
          key64[0][u] = 0ull; key64[1][u] = 0ull; key64[2][u] = 0ull; key64[3][u] = 0ull;
          lsum4[0][u] = 0.f; lsum4[1][u] = 0.f; lsum4[2][u] = 0.f; lsum4[3][u] = 0.f;
          fdSh4[0][u] = 0u; fdSh4[1][u] = 0u; fdSh4[2][u] = 0u; fdSh4[3][u] = 0u;
          logpv += ls;                               // lsum lags one step; totals identical
          uint32_t pk = upk;
          int r = (int)((pk >> 16) & 3) + 1;
          upk = ((pk | fda) & 0xFFFFu) | ((uint32_t)r << 16);
          float rf = (float)r;
          usv = w0 * (rf / 3.0f) + w1 * (fmaxf(3.0f - rf, 0.f) / 3.0f) +
                ((r == 2) ? w2 : 0.f);
          if ((win >> 2) == g) {
            int sl = win & 3;
            ab |= 1u << sl;
            float4 c = capS4[sl];        // unique (server,step) winner -> no race
            float4 nc = make_float4(fmaxf(c.x - nax, 0.f), fmaxf(c.y - nay, 0.f),
                                    fmaxf(c.z - nbx, 0.f), fmaxf(c.w - nby, 0.f));
            capS4[sl] = nc;
            float4 mv = minv4[sl];
            crS4[sl] = make_float4(nc.x / mv.x, nc.y / mv.y, nc.z / mv.z, nc.w / mv.w);
          }
        }
      }
      __syncthreads();                              // B4
    }
  }

  // ---- final flush: last step's deferred lsum + unconsumed residue ----
  if ((tid < 256) && prevValid) {
    unsigned long long Bw = __hip_atomic_load(&propB[prevSlot], __ATOMIC_RELAXED, AGENT);
    if ((unsigned)(Bw >> 32) != prevE) {
      int iters = 0;
      do {
        __builtin_amdgcn_s_sleep(1);
        Bw = __hip_atomic_load(&propB[prevSlot], __ATOMIC_RELAXED, AGENT);
        if (++iters > SPINCAP) break;
      } while ((unsigned)(Bw >> 32) != prevE);
    }
    atomicAdd(&lsum4[bank][prevPu], __uint_as_float((unsigned)Bw));
  }
  __syncthreads();
  logpv += lsum4[0][tid] + lsum4[1][tid] + lsum4[2][tid] + lsum4[3][tid];

  // ---- fused outputs: alloc expansion + cap + logp ----
  {
    float4 o;
    o.x = (ab & 1u) ? 1.f : 0.f;
    o.y = ((ab >> 1) & 1u) ? 1.f : 0.f;
    o.z = ((ab >> 2) & 1u) ? 1.f : 0.f;
    o.w = ((ab >> 3) & 1u) ? 1.f : 0.f;
    *(float4*)(out + 4 + (size_t)(b * NU + tid) * NS + g * 4) = o;
  }
  if (tid < SPB)
    *(float4*)(out + 4 + (size_t)NB * NU * NS + (size_t)(bs0 + tid) * 4) = capS4[tid];
  if (g == 0) {
    float a2 = logpv;
    for (int o = 32; o; o >>= 1) a2 += __shfl_xor(a2, o);
    if (ln64 == 0) wredL[wv] = a2;
    __syncthreads();
    if (tid == 0) {
      float s = 0.f;
#pragma unroll
      for (int i = 0; i < 16; ++i) s += wredL[i];
      out[b] = s;
    }
  }
}

extern "C" void kernel_launch(void* const* d_in, const int* in_sizes, int n_in,
                              void* d_out, int out_size, void* d_ws, size_t ws_size,
                              hipStream_t stream) {
  const float* user_enc = (const float*)d_in[0];
  const float* server_enc = (const float*)d_in[1];
  const float* users = (const float*)d_in[2];
  const float* servers = (const float*)d_in[3];
  const uint8_t* connect = (const uint8_t*)d_in[4];
  const float* fd_onehot = (const float*)d_in[5];
  const float* W_state = (const float*)d_in[6];
  const float* b_state = (const float*)d_in[7];
  const float* W_q = (const float*)d_in[8];
  const float* W_k = (const float*)d_in[9];
  const float* W_us = (const float*)d_in[10];
  const float* fd_alpha = (const float*)d_in[11];
  const float* fd_beta = (const float*)d_in[12];
  const float* score_bias = (const float*)d_in[13];

  char* ws = (char*)d_ws;
  size_t off = 0;
  auto take = [&](size_t bytes) -> void* {
    size_t cur = off;
    off = (off + bytes + 255) & ~(size_t)255;
    return (void*)(ws + cur);
  };
  unsigned long long* propA = (unsigned long long*)take((size_t)2 * NB * NS * 8);  // 16KB
  unsigned long long* propB = (unsigned long long*)take((size_t)2 * NB * NS * 8);  // 16KB (contiguous)
  float* q = (float*)take((size_t)NB * NU * ND * 4);
  float* kb = (float*)take((size_t)NB * NS * ND * 4);
  float* L0T = (float*)take((size_t)NB * NS * NU * 4);
  float* qc = (float*)take((size_t)NB * NU * 4 * 4);
  float* WS_K = (float*)take((size_t)ND * 4 * 4);
  uint32_t* connT = (uint32_t*)take((size_t)NB * NS * 32 * 4);
  float* outp = (float*)d_out;

  // 3 dispatches total
  k_pre1<<<450, 256, 0, stream>>>(connect, W_state, W_k, user_enc, server_enc, b_state,
                                  W_q, connT, WS_K, q, kb, (float4*)propA);
  k_pre2<<<1280, 256, 0, stream>>>(q, WS_K, qc, kb, L0T);
  k_steps4<<<NB * NGRP, NT, 0, stream>>>(
      L0T, qc, users, servers, connT, fd_onehot, W_us, fd_alpha, fd_beta, score_bias,
      propA, propB, outp);
}

// Round 21
// 170.468 us; speedup vs baseline: 1.1395x; 1.1395x over previous
//
#include <hip/hip_runtime.h>
#include <stdint.h>
#include <math.h>

#define NB 4
#define NU 1024
#define NS 256
#define NF 16
#define ND 256
#define NEGV -1000000000.0f
#define VBIT (1u << 14)
#define AGENT __HIP_MEMORY_SCOPE_AGENT
#define SPINCAP (1 << 20)
#define NGRP 64            // blocks per batch
#define SPB 4              // servers per block
#define NT 1024            // threads per step-block (16 waves)

// propA[par+bs]: bits0-9 argu | 10-13 fid | 14 valid | 15-20 epoch ; maxv bits << 32
// propB[par+bs]: low32 = -log(sum) bits ; high32 = epoch

// ---- shared 64x64 f32 GEMM body (double-buffered LDS; proven bit-identical) ----
__device__ __forceinline__ void gemm64_body(
    const float* __restrict__ A, const float* __restrict__ Bm, float* __restrict__ C,
    int K, int lda, int ldb, int ldc, const float* __restrict__ biasA, float alpha,
    int m0, int n0, int t,
    float (&As)[2][16][68], float (&Bs)[2][16][68]) {
  int tx = t & 15, ty = t >> 4;
  float acc[4][4];
#pragma unroll
  for (int i = 0; i < 4; i++)
#pragma unroll
    for (int j = 0; j < 4; j++) acc[i][j] = 0.f;
  int lr = t >> 2;
  int kq = (t & 3) * 4;
  {
    float4 av = *(const float4*)(A + (size_t)(m0 + lr) * lda + kq);
    if (biasA) {
      const float* bp = biasA + kq;
      av.x += bp[0]; av.y += bp[1]; av.z += bp[2]; av.w += bp[3];
    }
    As[0][kq + 0][lr] = av.x; As[0][kq + 1][lr] = av.y;
    As[0][kq + 2][lr] = av.z; As[0][kq + 3][lr] = av.w;
    float4 bv = *(const float4*)(Bm + (size_t)(n0 + lr) * ldb + kq);
    Bs[0][kq + 0][lr] = bv.x; Bs[0][kq + 1][lr] = bv.y;
    Bs[0][kq + 2][lr] = bv.z; Bs[0][kq + 3][lr] = bv.w;
  }
  __syncthreads();
  int nt = K >> 4;
  for (int ti = 0; ti < nt; ++ti) {
    int buf = ti & 1;
    float4 av2, bv2;
    bool more = (ti + 1 < nt);
    if (more) {
      int k0 = (ti + 1) << 4;
      av2 = *(const float4*)(A + (size_t)(m0 + lr) * lda + k0 + kq);
      if (biasA) {
        const float* bp = biasA + k0 + kq;
        av2.x += bp[0]; av2.y += bp[1]; av2.z += bp[2]; av2.w += bp[3];
      }
      bv2 = *(const float4*)(Bm + (size_t)(n0 + lr) * ldb + k0 + kq);
    }
#pragma unroll
    for (int k = 0; k < 16; ++k) {
      float4 a = *(const float4*)&As[buf][k][ty * 4];
      float4 bb = *(const float4*)&Bs[buf][k][tx * 4];
      float am[4] = {a.x, a.y, a.z, a.w};
      float bn[4] = {bb.x, bb.y, bb.z, bb.w};
#pragma unroll
      for (int i = 0; i < 4; ++i)
#pragma unroll
        for (int j = 0; j < 4; ++j) acc[i][j] += am[i] * bn[j];
    }
    if (more) {
      __syncthreads();
      int nb = buf ^ 1;
      As[nb][kq + 0][lr] = av2.x; As[nb][kq + 1][lr] = av2.y;
      As[nb][kq + 2][lr] = av2.z; As[nb][kq + 3][lr] = av2.w;
      Bs[nb][kq + 0][lr] = bv2.x; Bs[nb][kq + 1][lr] = bv2.y;
      Bs[nb][kq + 2][lr] = bv2.z; Bs[nb][kq + 3][lr] = bv2.w;
      __syncthreads();
    }
  }
#pragma unroll
  for (int i = 0; i < 4; ++i) {
    float4 o = make_float4(acc[i][0] * alpha, acc[i][1] * alpha,
                           acc[i][2] * alpha, acc[i][3] * alpha);
    *(float4*)(C + (size_t)(m0 + ty * 4 + i) * ldc + n0 + tx * 4) = o;
  }
}

// ---- pre1: transpose(+local dtype detect) | weights | q-gemm | kb-gemm | prop-zero ----
__global__ __launch_bounds__(256) void k_pre1(
    const uint8_t* __restrict__ conn, const float* __restrict__ W_state,
    const float* __restrict__ W_k, const float* __restrict__ user_enc,
    const float* __restrict__ server_enc, const float* __restrict__ b_state,
    const float* __restrict__ W_q,
    uint32_t* __restrict__ connT, float* __restrict__ WS_K,
    float* __restrict__ q, float* __restrict__ kb, float4* __restrict__ propZ) {
  __shared__ float As[2][16][68];
  __shared__ float Bs[2][16][68];
  int blk = blockIdx.x;
  int t = threadIdx.x;
  if (blk < 128) {
    __shared__ unsigned dd[2];
    unsigned c0 = 0, c123 = 0;
    for (int i = t; i < 4096; i += 256) {
      uchar4 v = ((const uchar4*)conn)[i];
      c0 |= v.x; c123 |= (unsigned)(v.y | v.z | v.w);
    }
    if (t == 0) { dd[0] = 0; dd[1] = 0; }
    __syncthreads();
    unsigned long long m0 = __ballot(c0 != 0), m1 = __ballot(c123 != 0);
    if ((t & 63) == 0) {
      if (m0) atomicOr(&dd[0], 1u);
      if (m1) atomicOr(&dd[1], 1u);
    }
    __syncthreads();
    int f = (dd[1] == 0) ? 0 : ((dd[0] == 0) ? 1 : 2);
    int b = blk >> 5, ug = blk & 31;
    int u0 = ug * 32;
    uint8_t* sm = (uint8_t*)&As[0][0][0];   // 8320B < 8704B
#pragma unroll 4
    for (int r = 0; r < 32; ++r) {
      int e = (b * NU + u0 + r) * NS + t;
      bool nz;
      if (f == 0)      nz = ((const int*)conn)[e] != 0;
      else if (f == 1) nz = ((const float*)conn)[e] != 0.0f;
      else             nz = conn[e] != 0;
      sm[r * 260 + t] = nz ? 1 : 0;
    }
    __syncthreads();
    uint32_t word = 0;
#pragma unroll
    for (int j = 0; j < 32; ++j) word |= (uint32_t)sm[j * 260 + t] << j;
    connT[(b * NS + t) * 32 + ug] = word;
  } else if (blk == 128) {
    int d = t;
    const float4* wk4 = (const float4*)(W_k + d * ND);
    const float4* ws4 = (const float4*)W_state;
    float a0 = 0, a1 = 0, a2 = 0, a3 = 0;
    for (int e4 = 0; e4 < ND / 4; ++e4) {
      float4 k4 = wk4[e4];
      float4 w0 = ws4[e4 * 4 + 0];
      a0 += k4.x * w0.x; a1 += k4.x * w0.y; a2 += k4.x * w0.z; a3 += k4.x * w0.w;
      float4 w1 = ws4[e4 * 4 + 1];
      a0 += k4.y * w1.x; a1 += k4.y * w1.y; a2 += k4.y * w1.z; a3 += k4.y * w1.w;
      float4 w2 = ws4[e4 * 4 + 2];
      a0 += k4.z * w2.x; a1 += k4.z * w2.y; a2 += k4.z * w2.z; a3 += k4.z * w2.w;
      float4 w3 = ws4[e4 * 4 + 3];
      a0 += k4.w * w3.x; a1 += k4.w * w3.y; a2 += k4.w * w3.z; a3 += k4.w * w3.w;
    }
    ((float4*)WS_K)[d] = make_float4(a0, a1, a2, a3);
  } else if (blk < 385) {
    int idx = blk - 129;           // q-gemm: M=4096, N=256 -> 64x4 tiles = 256 blocks
    gemm64_body(user_enc, W_q, q, ND, ND, ND, ND, nullptr, 1.f,
                (idx >> 2) * 64, (idx & 3) * 64, t, As, Bs);
  } else if (blk < 449) {
    int idx = blk - 385;           // kb-gemm: M=1024, N=256 -> 16x4 tiles = 64 blocks
    gemm64_body(server_enc, W_k, kb, ND, ND, ND, ND, b_state, 1.f,
                (idx >> 2) * 64, (idx & 3) * 64, t, As, Bs);
  } else {
    float4 z = make_float4(0.f, 0.f, 0.f, 0.f);
    for (int i = t; i < 2048; i += 256) propZ[i] = z;   // propA+propB 32KB contiguous
  }
}

// ---- pre2: qc | L0T-gemm ----
__global__ __launch_bounds__(256) void k_pre2(const float* __restrict__ q,
                                              const float* __restrict__ WS_K,
                                              float* __restrict__ qc,
                                              const float* __restrict__ kb,
                                              float* __restrict__ L0T) {
  __shared__ float As[2][16][68];
  __shared__ float Bs[2][16][68];
  int blk = blockIdx.x;
  int t = threadIdx.x;
  if (blk < 1024) {
    int row = blk * 4 + (t >> 6);
    int ln = t & 63;
    const float* qr = q + (size_t)row * ND;
    float a0 = 0, a1 = 0, a2 = 0, a3 = 0;
    for (int d = ln; d < ND; d += 64) {
      float qv = qr[d];
      float4 w = ((const float4*)WS_K)[d];
      a0 += qv * w.x; a1 += qv * w.y; a2 += qv * w.z; a3 += qv * w.w;
    }
    for (int o = 32; o; o >>= 1) {
      a0 += __shfl_xor(a0, o); a1 += __shfl_xor(a1, o);
      a2 += __shfl_xor(a2, o); a3 += __shfl_xor(a3, o);
    }
    if (ln == 0)
      ((float4*)qc)[row] = make_float4(a0 * 0.0625f, a1 * 0.0625f, a2 * 0.0625f, a3 * 0.0625f);
  } else {
    int idx = blk - 1024;          // L0T: per batch z, M=NS (4 tiles), N=NU (16 tiles)
    int z = idx >> 6;
    int rest = idx & 63;
    int m0 = (rest >> 4) * 64;
    int n0 = (rest & 15) * 64;
    gemm64_body(kb + (size_t)z * NS * ND, q + (size_t)z * NU * ND,
                L0T + (size_t)z * NS * NU, ND, ND, ND, NU, nullptr, 0.0625f,
                m0, n0, t, As, Bs);
  }
}

// ---- the 32-step allocator: round-19 structure (5 barriers/step, separate lse
//      pass, single 64-bit key atomic, deferred propB) ----
__global__ __launch_bounds__(NT) void k_steps4(
    const float* __restrict__ L0T, const float* __restrict__ qc,
    const float* __restrict__ users, const float* __restrict__ servers,
    const uint32_t* __restrict__ connT, const float* __restrict__ fd_onehot,
    const float* __restrict__ W_us, const float* __restrict__ fd_alpha,
    const float* __restrict__ fd_beta, const float* __restrict__ score_bias,
    unsigned long long* __restrict__ propA, unsigned long long* __restrict__ propB,
    float* __restrict__ out) {
  __shared__ float redM[SPB][NT];
  __shared__ int redA[SPB][NT];
  __shared__ unsigned long long key64[4][NU];   // 32KB: enc<<32 | (255-srv)
  __shared__ float lsum4[4][NU];
  __shared__ unsigned fdSh4[4][NU];
  __shared__ float4 capS4[SPB];
  __shared__ float4 crS4[SPB];
  __shared__ float4 minv4[SPB];
  __shared__ int fidS[SPB];
  __shared__ float pM[SPB][4];
  __shared__ int pA[SPB][4];
  __shared__ float pS[SPB][4];
  __shared__ float wredL[16];
  __shared__ int anyL[4];

  const int blk = blockIdx.x;
  // XCD-clustered bijection: batch b on XCD residues {2b, 2b+1}
  const int b = (blk & 7) >> 1;
  const int g = ((blk >> 3) << 1) | (blk & 1);
  const int tid = threadIdx.x;
  const int wv = tid >> 6, ln64 = tid & 63;
  const int bs0 = b * NS + g * SPB;
  const int bank = tid & 3;
  const int sW = wv >> 2, part = wv & 3;   // wave->server/quarter reduction mapping

  const float a_ = fd_alpha[0], be_ = fd_beta[0];
  const float t0 = tanhf(be_), t1 = tanhf(a_ + be_);
  const float sb = score_bias[0];
  const float w0 = W_us[0], w1 = W_us[1], w2 = W_us[2];

  if (tid < SPB) {
    int srow = bs0 + tid;
    int f = 0;
    for (int ff = 0; ff < NF; ++ff)
      if (fd_onehot[srow * NF + ff] > 0.5f) { f = ff; break; }
    fidS[tid] = f;
    float4 ic = make_float4(servers[srow * 8 + 3], servers[srow * 8 + 4],
                            servers[srow * 8 + 5], servers[srow * 8 + 6]);
    capS4[tid] = ic;
    float4 mv = make_float4(fmaxf(ic.x, 1e-6f), fmaxf(ic.y, 1e-6f),
                            fmaxf(ic.z, 1e-6f), fmaxf(ic.w, 1e-6f));
    minv4[tid] = mv;
    crS4[tid] = make_float4(ic.x / mv.x, ic.y / mv.y, ic.z / mv.z, ic.w / mv.w);
  }

  // per-thread user state: user u == tid of batch b
  const int gu = b * NU + tid;
  float4 q4 = *(const float4*)(qc + gu * 4);
  float2 nA = *(const float2*)(users + gu * 8 + 2);
  float2 nB2 = *(const float2*)(users + gu * 8 + 4);
  const float nax = nA.x, nay = nA.y, nbx = nB2.x, nby = nB2.y;
  float L0r[SPB];
  uint32_t upk = 0;                 // bits 0-15 fdmask, bits 16-17 rc
  float usv = w1;
  float logpv = 0.f;
  uint32_t cb = 0, ab = 0;          // bit s
  // deferred propB consumption state (tid<256 only meaningful)
  int prevPu = 0, prevSlot = 0;
  unsigned prevE = 0;
  bool prevValid = false;
#pragma unroll
  for (int s = 0; s < SPB; ++s) {
    L0r[s] = L0T[(size_t)(bs0 + s) * NU + tid];
    uint32_t word = connT[(bs0 + s) * 32 + (tid >> 5)];
    cb |= ((word >> (tid & 31)) & 1u) << s;
  }
  for (int i = tid; i < 4 * NU; i += NT) {
    (&key64[0][0])[i] = 0ull;
    (&lsum4[0][0])[i] = 0.f;
    (&fdSh4[0][0])[i] = 0u;
  }
  __syncthreads();

  for (int step = 0; step < 32; ++step) {
    unsigned e = (unsigned)(step + 1);
    // ---- phase A: per-thread logits for own user x 4 servers ----
    float cand[SPB];
#pragma unroll
    for (int s = 0; s < SPB; ++s) {
      float4 c = capS4[s];
      float4 cr = crS4[s];
      int fid = fidS[s];
      bool el = ((cb >> s) & 1u) && !((ab >> s) & 1u) &&
                ((upk & 0x30000u) != 0x30000u) &&
                c.x >= nax && c.y >= nay && c.z >= nbx && c.w >= nby;
      float tt = ((upk >> fid) & 1u) ? t0 : t1;
      float lg = L0r[s] + q4.x * cr.x + q4.y * cr.y + q4.z * cr.z + q4.w * cr.w +
                 sb + tt + usv;
      float cv = el ? lg : NEGV;
      cand[s] = cv;
      redM[s][tid] = cv;
      redA[s][tid] = (cv > NEGV) ? tid : 0x7fffffff;
    }
    __syncthreads();                               // B1
    // wave reduce: wave wv handles server sW, quarter part; stride-64 gathers
    {
      int base = part * 256 + ln64;
      float m = redM[sW][base]; int a = redA[sW][base];
#pragma unroll
      for (int j = 1; j < 4; ++j) {
        float v = redM[sW][base + 64 * j]; int aa = redA[sW][base + 64 * j];
        if (v > m || (v == m && aa < a)) { m = v; a = aa; }
      }
      for (int o = 32; o; o >>= 1) {
        float ov = __shfl_xor(m, o); int oa = __shfl_xor(a, o);
        if (ov > m || (ov == m && oa < a)) { m = ov; a = oa; }
      }
      if (ln64 == 0) { pM[sW][part] = m; pA[sW][part] = a; }
    }
    __syncthreads();                               // B2
    // every wave locally combines the 4 partials of its server (same order)
    float bm;
    {
      float m = pM[sW][0]; int a = pA[sW][0];
#pragma unroll
      for (int j = 1; j < 4; ++j) {
        float v = pM[sW][j]; int aa = pA[sW][j];
        if (v > m || (v == m && aa < a)) { m = v; a = aa; }
      }
      bm = m;
      if (part == 0 && ln64 == 0) {
        int au = (a == 0x7fffffff) ? 0 : a;
        unsigned validb = (m > -1e8f) ? VBIT : 0u;
        unsigned pinfo = (unsigned)au | ((unsigned)fidS[sW] << 10) | validb | (e << 15);
        unsigned long long Aw = (unsigned long long)pinfo |
                                ((unsigned long long)__float_as_uint(m) << 32);
        __hip_atomic_store(&propA[(step & 1) * (NB * NS) + bs0 + sW], Aw,
                           __ATOMIC_RELAXED, AGENT);
      }
      // fused lse: stride-64 gathers, exp against bm
      int base = part * 256 + ln64;
      float ps = expf(redM[sW][base] - bm) + expf(redM[sW][base + 64] - bm) +
                 expf(redM[sW][base + 128] - bm) + expf(redM[sW][base + 192] - bm);
      for (int o = 32; o; o >>= 1) ps += __shfl_xor(ps, o);
      if (ln64 == 0) pS[sW][part] = ps;
    }
    __syncthreads();                               // B3
    if (tid < SPB) {
      float ps = pS[tid][0] + pS[tid][1] + pS[tid][2] + pS[tid][3];
      unsigned long long Bw = (unsigned long long)__float_as_uint(-logf(ps)) |
                              ((unsigned long long)e << 32);
      __hip_atomic_store(&propB[(step & 1) * (NB * NS) + bs0 + tid], Bw,
                         __ATOMIC_RELAXED, AGENT);
    }

    // ---- phase B: single propA poll; one 64-bit key atomic; deferred propB ----
    {
      int par = (step & 1) * (NB * NS) + b * NS;
      unsigned pi = 0;
      if (tid < 256) {
        unsigned long long Aw = __hip_atomic_load(&propA[par + tid], __ATOMIC_RELAXED, AGENT);
        if ((((unsigned)Aw >> 15) & 63u) != e) {
          int iters = 0;
          do {
            __builtin_amdgcn_s_sleep(1);
            Aw = __hip_atomic_load(&propA[par + tid], __ATOMIC_RELAXED, AGENT);
            if (++iters > SPINCAP) break;
          } while ((((unsigned)Aw >> 15) & 63u) != e);
        }
        pi = (unsigned)Aw;
        int pu = pi & 1023;
        // deferred: add prev step's lsum contribution (propB long since visible)
        if (prevValid) {
          unsigned long long Bw = __hip_atomic_load(&propB[prevSlot], __ATOMIC_RELAXED, AGENT);
          if ((unsigned)(Bw >> 32) != prevE) {
            int iters = 0;
            do {
              __builtin_amdgcn_s_sleep(1);
              Bw = __hip_atomic_load(&propB[prevSlot], __ATOMIC_RELAXED, AGENT);
              if (++iters > SPINCAP) break;
            } while ((unsigned)(Bw >> 32) != prevE);
          }
          atomicAdd(&lsum4[bank][prevPu], __uint_as_float((unsigned)Bw));
        }
        prevValid = (pi & VBIT) != 0;
        prevPu = pu;
        prevSlot = par + tid;
        prevE = e;
        if (pi & VBIT) {
          unsigned vb = (unsigned)(Aw >> 32);
          unsigned enc = (vb & 0x80000000u) ? ~vb : (vb | 0x80000000u);
          unsigned long long key = ((unsigned long long)enc << 32) |
                                   (unsigned)(255 - tid);
          atomicMax(&key64[bank][pu], key);
          atomicOr(&fdSh4[bank][pu], 1u << ((pi >> 10) & 15));
        }
      }
      unsigned long long mm = __ballot((pi & VBIT) != 0);
      if (wv < 4 && ln64 == 0) anyL[wv] = (mm != 0ull) ? 1 : 0;
      __syncthreads();                              // B4: atomics + prevAdd done
      if (!(anyL[0] | anyL[1] | anyL[2] | anyL[3])) break;  // batch frozen forever
      {
        int u = tid;
        unsigned long long k0 = key64[0][u], k1 = key64[1][u];
        unsigned long long k2 = key64[2][u], k3 = key64[3][u];
        unsigned long long gmax = max(max(k0, k1), max(k2, k3));
        if (gmax) {
          int win = 255 - (int)(gmax & 0xFFull);
          float ls = lsum4[0][u] + lsum4[1][u] + lsum4[2][u] + lsum4[3][u];
          unsigned fda = fdSh4[0][u] | fdSh4[1][u] | fdSh4[2][u] | fdSh4[3][u];
          key64[0][u] = 0ull; key64[1][u] = 0ull; key64[2][u] = 0ull; key64[3][u] = 0ull;
          lsum4[0][u] = 0.f; lsum4[1][u] = 0.f; lsum4[2][u] = 0.f; lsum4[3][u] = 0.f;
          fdSh4[0][u] = 0u; fdSh4[1][u] = 0u; fdSh4[2][u] = 0u; fdSh4[3][u] = 0u;
          logpv += ls;                               // lsum lags one step; totals identical
          uint32_t pk = upk;
          int r = (int)((pk >> 16) & 3) + 1;
          upk = ((pk | fda) & 0xFFFFu) | ((uint32_t)r << 16);
          float rf = (float)r;
          usv = w0 * (rf / 3.0f) + w1 * (fmaxf(3.0f - rf, 0.f) / 3.0f) +
                ((r == 2) ? w2 : 0.f);
          if ((win >> 2) == g) {
            int sl = win & 3;
            ab |= 1u << sl;
            float4 c = capS4[sl];        // unique (server,step) winner -> no race
            float4 nc = make_float4(fmaxf(c.x - nax, 0.f), fmaxf(c.y - nay, 0.f),
                                    fmaxf(c.z - nbx, 0.f), fmaxf(c.w - nby, 0.f));
            capS4[sl] = nc;
            float4 mv = minv4[sl];
            crS4[sl] = make_float4(nc.x / mv.x, nc.y / mv.y, nc.z / mv.z, nc.w / mv.w);
          }
        }
      }
      __syncthreads();                              // B5
    }
  }

  // ---- final flush: last step's deferred lsum + unconsumed residue ----
  if ((tid < 256) && prevValid) {
    unsigned long long Bw = __hip_atomic_load(&propB[prevSlot], __ATOMIC_RELAXED, AGENT);
    if ((unsigned)(Bw >> 32) != prevE) {
      int iters = 0;
      do {
        __builtin_amdgcn_s_sleep(1);
        Bw = __hip_atomic_load(&propB[prevSlot], __ATOMIC_RELAXED, AGENT);
        if (++iters > SPINCAP) break;
      } while ((unsigned)(Bw >> 32) != prevE);
    }
    atomicAdd(&lsum4[bank][prevPu], __uint_as_float((unsigned)Bw));
  }
  __syncthreads();
  logpv += lsum4[0][tid] + lsum4[1][tid] + lsum4[2][tid] + lsum4[3][tid];

  // ---- fused outputs: alloc expansion + cap + logp ----
  {
    float4 o;
    o.x = (ab & 1u) ? 1.f : 0.f;
    o.y = ((ab >> 1) & 1u) ? 1.f : 0.f;
    o.z = ((ab >> 2) & 1u) ? 1.f : 0.f;
    o.w = ((ab >> 3) & 1u) ? 1.f : 0.f;
    *(float4*)(out + 4 + (size_t)(b * NU + tid) * NS + g * 4) = o;
  }
  if (tid < SPB)
    *(float4*)(out + 4 + (size_t)NB * NU * NS + (size_t)(bs0 + tid) * 4) = capS4[tid];
  if (g == 0) {
    float a2 = logpv;
    for (int o = 32; o; o >>= 1) a2 += __shfl_xor(a2, o);
    if (ln64 == 0) wredL[wv] = a2;
    __syncthreads();
    if (tid == 0) {
      float s = 0.f;
#pragma unroll
      for (int i = 0; i < 16; ++i) s += wredL[i];
      out[b] = s;
    }
  }
}

extern "C" void kernel_launch(void* const* d_in, const int* in_sizes, int n_in,
                              void* d_out, int out_size, void* d_ws, size_t ws_size,
                              hipStream_t stream) {
  const float* user_enc = (const float*)d_in[0];
  const float* server_enc = (const float*)d_in[1];
  const float* users = (const float*)d_in[2];
  const float* servers = (const float*)d_in[3];
  const uint8_t* connect = (const uint8_t*)d_in[4];
  const float* fd_onehot = (const float*)d_in[5];
  const float* W_state = (const float*)d_in[6];
  const float* b_state = (const float*)d_in[7];
  const float* W_q = (const float*)d_in[8];
  const float* W_k = (const float*)d_in[9];
  const float* W_us = (const float*)d_in[10];
  const float* fd_alpha = (const float*)d_in[11];
  const float* fd_beta = (const float*)d_in[12];
  const float* score_bias = (const float*)d_in[13];

  char* ws = (char*)d_ws;
  size_t off = 0;
  auto take = [&](size_t bytes) -> void* {
    size_t cur = off;
    off = (off + bytes + 255) & ~(size_t)255;
    return (void*)(ws + cur);
  };
  unsigned long long* propA = (unsigned long long*)take((size_t)2 * NB * NS * 8);  // 16KB
  unsigned long long* propB = (unsigned long long*)take((size_t)2 * NB * NS * 8);  // 16KB (contiguous)
  float* q = (float*)take((size_t)NB * NU * ND * 4);
  float* kb = (float*)take((size_t)NB * NS * ND * 4);
  float* L0T = (float*)take((size_t)NB * NS * NU * 4);
  float* qc = (float*)take((size_t)NB * NU * 4 * 4);
  float* WS_K = (float*)take((size_t)ND * 4 * 4);
  uint32_t* connT = (uint32_t*)take((size_t)NB * NS * 32 * 4);
  float* outp = (float*)d_out;

  // 3 dispatches total
  k_pre1<<<450, 256, 0, stream>>>(connect, W_state, W_k, user_enc, server_enc, b_state,
                                  W_q, connT, WS_K, q, kb, (float4*)propA);
  k_pre2<<<1280, 256, 0, stream>>>(q, WS_K, qc, kb, L0T);
  k_steps4<<<NB * NGRP, NT, 0, stream>>>(
      L0T, qc, users, servers, connT, fd_onehot, W_us, fd_alpha, fd_beta, score_bias,
      propA, propB, outp);
}